// Round 22
// baseline (21.027 us; speedup 1.0000x reference)
//
#include <hip/hip_runtime.h>

#define NPART 128
#define NDIM  128
#define BATCH 4096
#define BPP   4                       // blocks per particle
#define NBLK  (NPART * BPP)           // 512 blocks
#define NXCD  8

#define DOT8(accA,accB,accC,accD,SRB,Y0,Y1,Y2,Y3,Y4,Y5,Y6,Y7)                 \
    accA += sr[SRB+0].x*Y0.x; accB += sr[SRB+0].y*Y0.y;                       \
    accC += sr[SRB+0].z*Y0.z; accD += sr[SRB+0].w*Y0.w;                       \
    accA += sr[SRB+1].x*Y1.x; accB += sr[SRB+1].y*Y1.y;                       \
    accC += sr[SRB+1].z*Y1.z; accD += sr[SRB+1].w*Y1.w;                       \
    accA += sr[SRB+2].x*Y2.x; accB += sr[SRB+2].y*Y2.y;                       \
    accC += sr[SRB+2].z*Y2.z; accD += sr[SRB+2].w*Y2.w;                       \
    accA += sr[SRB+3].x*Y3.x; accB += sr[SRB+3].y*Y3.y;                       \
    accC += sr[SRB+3].z*Y3.z; accD += sr[SRB+3].w*Y3.w;                       \
    accA += sr[SRB+4].x*Y4.x; accB += sr[SRB+4].y*Y4.y;                       \
    accC += sr[SRB+4].z*Y4.z; accD += sr[SRB+4].w*Y4.w;                       \
    accA += sr[SRB+5].x*Y5.x; accB += sr[SRB+5].y*Y5.y;                       \
    accC += sr[SRB+5].z*Y5.z; accD += sr[SRB+5].w*Y5.w;                       \
    accA += sr[SRB+6].x*Y6.x; accB += sr[SRB+6].y*Y6.y;                       \
    accC += sr[SRB+6].z*Y6.z; accD += sr[SRB+6].w*Y6.w;                       \
    accA += sr[SRB+7].x*Y7.x; accB += sr[SRB+7].y*Y7.y;                       \
    accC += sr[SRB+7].z*Y7.z; accD += sr[SRB+7].w*Y7.w;

// ---------------------------------------------------------------------------
// R19 structure with ONE change: sigma LDS staging DELETED. Thread i loads
// its own sigma row directly into sr[32] (8 lines, issued right after the
// mk loads so selection covers the latency). Rationale: the LDS tile had
// ZERO cross-thread reuse (thread i read only row i) — it was a coalescing
// relay costing a full-drain barrier + 96 LDS ops/thread + 64 KB LDS.
// Barrier #2 remains only for slist. Per-sample y pipeline unchanged.
// ---------------------------------------------------------------------------
__global__ __launch_bounds__(256)
void mix_kernel(const float* __restrict__ gaussian,  // [BATCH, NDIM]
                const float* __restrict__ logp,      // [NPART]
                const float* __restrict__ pos,       // [NPART, NDIM]
                const float* __restrict__ sigma,     // [NPART, NDIM, NDIM]
                const int*   __restrict__ randind,   // [BATCH]
                float* __restrict__ out,             // [BATCH, NDIM]
                float* __restrict__ wout,            // [BATCH]
                float* __restrict__ indout) {        // [BATCH]
    const int g  = blockIdx.x;
    const int sg = (g % NXCD) * (NBLK / NXCD) + g / NXCD;
    const int p  = sg >> 2;            // particle
    const int q  = sg & 3;             // quarter of bucket
    const int t  = threadIdx.x;
    const int i  = t & 127;            // output row
    const int hf = t >> 7;             // sample-parity half
    const int lane = t & 63, wid = t >> 6;

    __shared__ int    wtot[4];
    __shared__ int    slist[160];                // sids of my quarter
    __shared__ float  smx[2];                    // softmax m, S

    // ---- 1. selection loads first: thread t owns samples [16t, 16t+16) ----
    const int4* rnd4 = reinterpret_cast<const int4*>(randind);
    int mk[16];
    {
        int4 a = rnd4[t * 4 + 0], b = rnd4[t * 4 + 1],
             c = rnd4[t * 4 + 2], d = rnd4[t * 4 + 3];
        mk[0]=a.x;  mk[1]=a.y;  mk[2]=a.z;  mk[3]=a.w;
        mk[4]=b.x;  mk[5]=b.y;  mk[6]=b.z;  mk[7]=b.w;
        mk[8]=c.x;  mk[9]=c.y;  mk[10]=c.z; mk[11]=c.w;
        mk[12]=d.x; mk[13]=d.y; mk[14]=d.z; mk[15]=d.w;
    }

    // ---- 2. sigma row i -> sr[32] DIRECT (issues now; selection covers) ----
    float4 sr[32];
    {
        const float4* srow = reinterpret_cast<const float4*>(
            sigma + (size_t)p * NDIM * NDIM + (size_t)i * NDIM);
        #pragma unroll
        for (int u = 0; u < 32; ++u) sr[u] = srow[u];
    }

    // ---- 3. softmax scalars by wave 0 ----
    if (t < 64) {
        float a = logp[t], b = logp[t + 64];
        float m = fmaxf(a, b);
        #pragma unroll
        for (int o = 32; o > 0; o >>= 1) m = fmaxf(m, __shfl_xor(m, o));
        float ea = expf(a - m), eb = expf(b - m);
        float s = ea + eb;
        #pragma unroll
        for (int o = 32; o > 0; o >>= 1) s += __shfl_xor(s, o);
        if (t == 0) { smx[0] = m; smx[1] = s; }
    }

    // ---- 4. wave-shfl scan selection ----
    int cnt = 0;
    #pragma unroll
    for (int k = 0; k < 16; ++k) cnt += (mk[k] == p) ? 1 : 0;
    int v = cnt;                                   // inclusive wave scan
    #pragma unroll
    for (int o = 1; o < 64; o <<= 1) {
        int u = __shfl_up(v, o);
        if (lane >= o) v += u;
    }
    if (lane == 63) wtot[wid] = v;
    __syncthreads();                               // barrier #1
    int woff = 0;
    #pragma unroll
    for (int w = 0; w < 4; ++w) woff += (w < wid) ? wtot[w] : 0;
    const int base = woff + v - cnt;               // block-wide exclusive
    const int n    = wtot[0] + wtot[1] + wtot[2] + wtot[3];
    const int lo   = (n * q) / BPP;
    const int hi   = (n * (q + 1)) / BPP;
    const int nq   = hi - lo;
    if (nq == 0) return;               // uniform across block, safe

    // ---- 5. rank loop ----
    const float pw = expf(logp[p] - smx[0]) / smx[1];
    {
        int r = base;
        #pragma unroll
        for (int k = 0; k < 16; ++k) {
            if (mk[k] == p) {
                if (r >= lo && r < hi) slist[r - lo] = t * 16 + k;
                ++r;
            }
        }
    }
    const float posv = pos[p * NDIM + i];
    __syncthreads();                               // barrier #2 (slist ready)

    // ---- 6. pipelined per-sample loop (A/B quarter-row double buffer) ----
    int s = hf;
    if (s < nq) {
        const float4* y = reinterpret_cast<const float4*>(
            gaussian + (size_t)__builtin_amdgcn_readfirstlane(slist[s]) * NDIM);
        float4 A0=y[0],A1=y[1],A2=y[2],A3=y[3],A4=y[4],A5=y[5],A6=y[6],A7=y[7];
        float4 B0,B1,B2,B3,B4,B5,B6,B7;
        for (; s < nq; s += 2) {
            const int sid = __builtin_amdgcn_readfirstlane(slist[s]);
            y = reinterpret_cast<const float4*>(gaussian + (size_t)sid * NDIM);
            const int sn = (s + 2 < nq) ? __builtin_amdgcn_readfirstlane(slist[s + 2]) : sid;
            const float4* yn = reinterpret_cast<const float4*>(
                gaussian + (size_t)sn * NDIM);
            float a0 = 0.f, a1 = 0.f, a2 = 0.f, a3 = 0.f;
            B0=y[8];B1=y[9];B2=y[10];B3=y[11];B4=y[12];B5=y[13];B6=y[14];B7=y[15];
            DOT8(a0,a1,a2,a3, 0, A0,A1,A2,A3,A4,A5,A6,A7)
            A0=y[16];A1=y[17];A2=y[18];A3=y[19];A4=y[20];A5=y[21];A6=y[22];A7=y[23];
            DOT8(a0,a1,a2,a3, 8, B0,B1,B2,B3,B4,B5,B6,B7)
            B0=y[24];B1=y[25];B2=y[26];B3=y[27];B4=y[28];B5=y[29];B6=y[30];B7=y[31];
            DOT8(a0,a1,a2,a3, 16, A0,A1,A2,A3,A4,A5,A6,A7)
            A0=yn[0];A1=yn[1];A2=yn[2];A3=yn[3];A4=yn[4];A5=yn[5];A6=yn[6];A7=yn[7];
            DOT8(a0,a1,a2,a3, 24, B0,B1,B2,B3,B4,B5,B6,B7)
            out[sid * NDIM + i] = posv + ((a0 + a1) + (a2 + a3));
            if (i == 0) {
                wout[sid]   = pw;
                indout[sid] = (float)p;            // exact for 0..127
            }
        }
    }
}

extern "C" void kernel_launch(void* const* d_in, const int* in_sizes, int n_in,
                              void* d_out, int out_size, void* d_ws, size_t ws_size,
                              hipStream_t stream) {
    const float* gaussian = (const float*)d_in[0];   // [4096,128]
    const float* logp     = (const float*)d_in[1];   // [128,1]
    const float* pos      = (const float*)d_in[2];   // [128,128]
    const float* sigma    = (const float*)d_in[3];   // [128,128,128]
    const int*   randind  = (const int*)d_in[4];     // [4096]

    float* out    = (float*)d_out;            // [4096*128]
    float* wout   = out + BATCH * NDIM;       // [4096]
    float* indout = wout + BATCH;             // [4096]

    mix_kernel<<<NBLK, 256, 0, stream>>>(gaussian, logp, pos, sigma, randind,
                                         out, wout, indout);
}

// Round 24
// 16.029 us; speedup vs baseline: 1.3118x; 1.3118x over previous
//
#include <hip/hip_runtime.h>

#define NPART 128
#define NDIM  128
#define BATCH 4096
#define BPP   4                       // blocks per particle
#define NBLK  (NPART * BPP)           // 512 blocks
#define NXCD  8

typedef __fp16 half2v __attribute__((ext_vector_type(2)));

// ---------------------------------------------------------------------------
// R19 structure, sigma/y demoted to f16 math (threshold is 2.54 — huge
// headroom; expect absmax ~0.05). Two occupancy caps fall together:
//   LDS tile 64->32 KB (f16)  => 4 blocks/CU by LDS
//   sr[] 128->64 VGPR (half2) => fits under launch_bounds(256,4) cap of 128
// Stage: reg-stage f32 pairs -> cvt_pkrtz -> swizzled ds_write_b128.
// Inner loop: y float4 -> 2 cvt_pkrtz -> 2 fdot2 (f32 accumulate), 4 chains.
// Selection / rank / wout/indout identical to R19.
// ---------------------------------------------------------------------------
__global__ __launch_bounds__(256, 4)
void mix_kernel(const float* __restrict__ gaussian,  // [BATCH, NDIM]
                const float* __restrict__ logp,      // [NPART]
                const float* __restrict__ pos,       // [NPART, NDIM]
                const float* __restrict__ sigma,     // [NPART, NDIM, NDIM]
                const int*   __restrict__ randind,   // [BATCH]
                float* __restrict__ out,             // [BATCH, NDIM]
                float* __restrict__ wout,            // [BATCH]
                float* __restrict__ indout) {        // [BATCH]
    const int g  = blockIdx.x;
    const int sg = (g % NXCD) * (NBLK / NXCD) + g / NXCD;
    const int p  = sg >> 2;            // particle
    const int q  = sg & 3;             // quarter of bucket
    const int t  = threadIdx.x;
    const int i  = t & 127;            // output row
    const int hf = t >> 7;             // sample-parity half
    const int lane = t & 63, wid = t >> 6;

    __shared__ float4 tile16[NDIM * 16];         // 32 KB: f16 sigma, swizzled
    __shared__ int    wtot[4];
    __shared__ int    slist[160];                // sids of my quarter
    __shared__ float  smx[2];                    // softmax m, S

    // ---- 1. selection loads first: thread t owns samples [16t, 16t+16) ----
    const int4* rnd4 = reinterpret_cast<const int4*>(randind);
    int mk[16];
    {
        int4 a = rnd4[t * 4 + 0], b = rnd4[t * 4 + 1],
             c = rnd4[t * 4 + 2], d = rnd4[t * 4 + 3];
        mk[0]=a.x;  mk[1]=a.y;  mk[2]=a.z;  mk[3]=a.w;
        mk[4]=b.x;  mk[5]=b.y;  mk[6]=b.z;  mk[7]=b.w;
        mk[8]=c.x;  mk[9]=c.y;  mk[10]=c.z; mk[11]=c.w;
        mk[12]=d.x; mk[13]=d.y; mk[14]=d.z; mk[15]=d.w;
    }

    // ---- 2. softmax scalars by wave 0 ----
    if (t < 64) {
        float a = logp[t], b = logp[t + 64];
        float m = fmaxf(a, b);
        #pragma unroll
        for (int o = 32; o > 0; o >>= 1) m = fmaxf(m, __shfl_xor(m, o));
        float ea = expf(a - m), eb = expf(b - m);
        float s = ea + eb;
        #pragma unroll
        for (int o = 32; o > 0; o >>= 1) s += __shfl_xor(s, o);
        if (t == 0) { smx[0] = m; smx[1] = s; }
    }

    // ---- 3. wave-shfl scan selection ----
    int cnt = 0;
    #pragma unroll
    for (int k = 0; k < 16; ++k) cnt += (mk[k] == p) ? 1 : 0;
    int v = cnt;                                   // inclusive wave scan
    #pragma unroll
    for (int o = 1; o < 64; o <<= 1) {
        int u = __shfl_up(v, o);
        if (lane >= o) v += u;
    }
    if (lane == 63) wtot[wid] = v;
    __syncthreads();                               // barrier #1
    int woff = 0;
    #pragma unroll
    for (int w = 0; w < 4; ++w) woff += (w < wid) ? wtot[w] : 0;
    const int base = woff + v - cnt;               // block-wide exclusive
    const int n    = wtot[0] + wtot[1] + wtot[2] + wtot[3];
    const int lo   = (n * q) / BPP;
    const int hi   = (n * (q + 1)) / BPP;
    const int nq   = hi - lo;
    if (nq == 0) return;               // uniform across block, safe

    // ---- 4a. rank loop (pure VALU on mk) ----
    const float pw = expf(logp[p] - smx[0]) / smx[1];
    {
        int r = base;
        #pragma unroll
        for (int k = 0; k < 16; ++k) {
            if (mk[k] == p) {
                if (r >= lo && r < hi) slist[r - lo] = t * 16 + k;
                ++r;
            }
        }
    }

    // ---- 4b. stage sigma: f32 pair loads -> f16 -> swizzled LDS ----
    // thread t, group w: float4 pair (w*512+2t, +1) -> f16 slot w*256+t.
    {
        const float4* src = reinterpret_cast<const float4*>(
            sigma + (size_t)p * NDIM * NDIM);
        float4 stg[16];
        #pragma unroll
        for (int w = 0; w < 8; ++w) {
            stg[2 * w]     = src[w * 512 + 2 * t];
            stg[2 * w + 1] = src[w * 512 + 2 * t + 1];
        }
        #pragma unroll
        for (int w = 0; w < 8; ++w) {
            half2v h0 = __builtin_amdgcn_cvt_pkrtz(stg[2*w].x,   stg[2*w].y);
            half2v h1 = __builtin_amdgcn_cvt_pkrtz(stg[2*w].z,   stg[2*w].w);
            half2v h2 = __builtin_amdgcn_cvt_pkrtz(stg[2*w+1].x, stg[2*w+1].y);
            half2v h3 = __builtin_amdgcn_cvt_pkrtz(stg[2*w+1].z, stg[2*w+1].w);
            float4 o;
            o.x = __builtin_bit_cast(float, h0);
            o.y = __builtin_bit_cast(float, h1);
            o.z = __builtin_bit_cast(float, h2);
            o.w = __builtin_bit_cast(float, h3);
            const int slot = w * 256 + t;          // linear 16B-f16 slot
            const int r = slot >> 4, u = slot & 15;
            tile16[r * 16 + (u ^ (r & 15))] = o;
        }
    }
    const float posv = pos[p * NDIM + i];
    __syncthreads();                               // barrier #2

    // ---- 5. row i -> 64 half2 regs (swizzled b128 reads) ----
    half2v srh[64];
    #pragma unroll
    for (int u = 0; u < 16; ++u) {
        float4 tmp = tile16[i * 16 + (u ^ (i & 15))];
        srh[4*u+0] = __builtin_bit_cast(half2v, tmp.x);
        srh[4*u+1] = __builtin_bit_cast(half2v, tmp.y);
        srh[4*u+2] = __builtin_bit_cast(half2v, tmp.z);
        srh[4*u+3] = __builtin_bit_cast(half2v, tmp.w);
    }

    // ---- 6. per-sample: y -> f16 -> fdot2 (4 f32 chains) ----
    for (int s = hf; s < nq; s += 2) {
        const int sid = __builtin_amdgcn_readfirstlane(slist[s]);
        const float4* y = reinterpret_cast<const float4*>(
            gaussian + (size_t)sid * NDIM);
        float a0 = 0.f, a1 = 0.f, a2 = 0.f, a3 = 0.f;
        #pragma unroll
        for (int jj = 0; jj < 32; ++jj) {
            float4 yv = y[jj];                     // wave-uniform address
            half2v h0 = __builtin_amdgcn_cvt_pkrtz(yv.x, yv.y);
            half2v h1 = __builtin_amdgcn_cvt_pkrtz(yv.z, yv.w);
            if (jj & 1) {
                a2 = __builtin_amdgcn_fdot2(srh[2*jj],   h0, a2, false);
                a3 = __builtin_amdgcn_fdot2(srh[2*jj+1], h1, a3, false);
            } else {
                a0 = __builtin_amdgcn_fdot2(srh[2*jj],   h0, a0, false);
                a1 = __builtin_amdgcn_fdot2(srh[2*jj+1], h1, a1, false);
            }
        }
        out[sid * NDIM + i] = posv + ((a0 + a1) + (a2 + a3));
        if (i == 0) {
            wout[sid]   = pw;
            indout[sid] = (float)p;                // exact for 0..127
        }
    }
}

extern "C" void kernel_launch(void* const* d_in, const int* in_sizes, int n_in,
                              void* d_out, int out_size, void* d_ws, size_t ws_size,
                              hipStream_t stream) {
    const float* gaussian = (const float*)d_in[0];   // [4096,128]
    const float* logp     = (const float*)d_in[1];   // [128,1]
    const float* pos      = (const float*)d_in[2];   // [128,128]
    const float* sigma    = (const float*)d_in[3];   // [128,128,128]
    const int*   randind  = (const int*)d_in[4];     // [4096]

    float* out    = (float*)d_out;            // [4096*128]
    float* wout   = out + BATCH * NDIM;       // [4096]
    float* indout = wout + BATCH;             // [4096]

    mix_kernel<<<NBLK, 256, 0, stream>>>(gaussian, logp, pos, sigma, randind,
                                         out, wout, indout);
}

// Round 25
// 15.431 us; speedup vs baseline: 1.3626x; 1.0388x over previous
//
#include <hip/hip_runtime.h>

#define NPART 128
#define NDIM  128
#define BATCH 4096
#define BPP   4                       // blocks per particle
#define NBLK  (NPART * BPP)           // 512 blocks
#define NXCD  8

typedef __attribute__((address_space(1))) const unsigned int guint;
typedef __attribute__((address_space(3))) unsigned int luint;

#define DOT8(accA,accB,accC,accD,SRB,Y0,Y1,Y2,Y3,Y4,Y5,Y6,Y7)                 \
    accA += sr[SRB+0].x*Y0.x; accB += sr[SRB+0].y*Y0.y;                       \
    accC += sr[SRB+0].z*Y0.z; accD += sr[SRB+0].w*Y0.w;                       \
    accA += sr[SRB+1].x*Y1.x; accB += sr[SRB+1].y*Y1.y;                       \
    accC += sr[SRB+1].z*Y1.z; accD += sr[SRB+1].w*Y1.w;                       \
    accA += sr[SRB+2].x*Y2.x; accB += sr[SRB+2].y*Y2.y;                       \
    accC += sr[SRB+2].z*Y2.z; accD += sr[SRB+2].w*Y2.w;                       \
    accA += sr[SRB+3].x*Y3.x; accB += sr[SRB+3].y*Y3.y;                       \
    accC += sr[SRB+3].z*Y3.z; accD += sr[SRB+3].w*Y3.w;                       \
    accA += sr[SRB+4].x*Y4.x; accB += sr[SRB+4].y*Y4.y;                       \
    accC += sr[SRB+4].z*Y4.z; accD += sr[SRB+4].w*Y4.w;                       \
    accA += sr[SRB+5].x*Y5.x; accB += sr[SRB+5].y*Y5.y;                       \
    accC += sr[SRB+5].z*Y5.z; accD += sr[SRB+5].w*Y5.w;                       \
    accA += sr[SRB+6].x*Y6.x; accB += sr[SRB+6].y*Y6.y;                       \
    accC += sr[SRB+6].z*Y6.z; accD += sr[SRB+6].w*Y6.w;                       \
    accA += sr[SRB+7].x*Y7.x; accB += sr[SRB+7].y*Y7.y;                       \
    accC += sr[SRB+7].z*Y7.z; accD += sr[SRB+7].w*Y7.w;

// ---------------------------------------------------------------------------
// FINAL (= R19, best measured: 15.12us). Single fused kernel, 512 blocks x
// 256 threads, block = (particle p, quarter q).
//   1. randind int4 loads first; softmax scalars on wave 0.
//   2. wave-shfl scan selection (rank = sid order -> deterministic exact
//      partition across the 4 sibling blocks; no atomics, no workspace).
//   3. sigma -> LDS via global_load_lds with pre-swizzled per-lane SOURCE
//      (G21/m173), XOR(r&31) involution; rank loop runs under the stream;
//      one drain barrier.
//   4. row i -> sr[32] via swizzled ds_read_b128.
//   5. per-sample loop software-pipelined with named-register A/B
//      quarter-row double buffer (y latency overlapped with FMAs).
// Verdict after 24 rounds: latency/launch-bound plateau — VALUBusy ~8%,
// HBM ~2%, no bank conflicts; TLP (f16/occupancy), MLP, and restructuring
// levers all counter-tested and exhausted.
// ---------------------------------------------------------------------------
__global__ __launch_bounds__(256)
void mix_kernel(const float* __restrict__ gaussian,  // [BATCH, NDIM]
                const float* __restrict__ logp,      // [NPART]
                const float* __restrict__ pos,       // [NPART, NDIM]
                const float* __restrict__ sigma,     // [NPART, NDIM, NDIM]
                const int*   __restrict__ randind,   // [BATCH]
                float* __restrict__ out,             // [BATCH, NDIM]
                float* __restrict__ wout,            // [BATCH]
                float* __restrict__ indout) {        // [BATCH]
    const int g  = blockIdx.x;
    const int sg = (g % NXCD) * (NBLK / NXCD) + g / NXCD;
    const int p  = sg >> 2;            // particle
    const int q  = sg & 3;             // quarter of bucket
    const int t  = threadIdx.x;
    const int i  = t & 127;            // output row
    const int hf = t >> 7;             // sample-parity half
    const int lane = t & 63, wid = t >> 6;

    __shared__ float4 smat[NDIM * 32];           // 64 KB swizzled sigma_p
    __shared__ int    wtot[4];
    __shared__ int    slist[160];                // sids of my quarter
    __shared__ float  smx[2];                    // softmax m, S

    // ---- 1. selection loads first: thread t owns samples [16t, 16t+16) ----
    const int4* rnd4 = reinterpret_cast<const int4*>(randind);
    int mk[16];
    {
        int4 a = rnd4[t * 4 + 0], b = rnd4[t * 4 + 1],
             c = rnd4[t * 4 + 2], d = rnd4[t * 4 + 3];
        mk[0]=a.x;  mk[1]=a.y;  mk[2]=a.z;  mk[3]=a.w;
        mk[4]=b.x;  mk[5]=b.y;  mk[6]=b.z;  mk[7]=b.w;
        mk[8]=c.x;  mk[9]=c.y;  mk[10]=c.z; mk[11]=c.w;
        mk[12]=d.x; mk[13]=d.y; mk[14]=d.z; mk[15]=d.w;
    }

    // ---- 2. softmax scalars by wave 0 ----
    if (t < 64) {
        float a = logp[t], b = logp[t + 64];
        float m = fmaxf(a, b);
        #pragma unroll
        for (int o = 32; o > 0; o >>= 1) m = fmaxf(m, __shfl_xor(m, o));
        float ea = expf(a - m), eb = expf(b - m);
        float s = ea + eb;
        #pragma unroll
        for (int o = 32; o > 0; o >>= 1) s += __shfl_xor(s, o);
        if (t == 0) { smx[0] = m; smx[1] = s; }
    }

    // ---- 3. wave-shfl scan selection ----
    int cnt = 0;
    #pragma unroll
    for (int k = 0; k < 16; ++k) cnt += (mk[k] == p) ? 1 : 0;
    int v = cnt;                                   // inclusive wave scan
    #pragma unroll
    for (int o = 1; o < 64; o <<= 1) {
        int u = __shfl_up(v, o);
        if (lane >= o) v += u;
    }
    if (lane == 63) wtot[wid] = v;
    __syncthreads();                               // barrier #1
    int woff = 0;
    #pragma unroll
    for (int w = 0; w < 4; ++w) woff += (w < wid) ? wtot[w] : 0;
    const int base = woff + v - cnt;               // block-wide exclusive
    const int n    = wtot[0] + wtot[1] + wtot[2] + wtot[3];
    const int lo   = (n * q) / BPP;
    const int hi   = (n * (q + 1)) / BPP;
    const int nq   = hi - lo;
    if (nq == 0) return;               // uniform across block, safe

    // ---- 4a. issue sigma -> LDS async, pre-swizzled source (G21/m173) ----
    {
        const float4* src = reinterpret_cast<const float4*>(sigma)
                            + (size_t)p * 4096;
        #pragma unroll
        for (int w = 0; w < 16; ++w) {
            const int idx = w * 256 + t;           // linear float4 LDS slot
            const int r = idx >> 5, c = idx & 31;
            const float4* gp = src + (r * 32 + (c ^ (r & 31)));
            luint* lp = (luint*)(smat + (w * 256 + wid * 64)); // wave-uniform
            __builtin_amdgcn_global_load_lds((guint*)gp, lp, 16, 0, 0);
        }
    }

    // ---- 4b. rank loop (runs while sigma streams) ----
    const float pw = expf(logp[p] - smx[0]) / smx[1];
    {
        int r = base;
        #pragma unroll
        for (int k = 0; k < 16; ++k) {
            if (mk[k] == p) {
                if (r >= lo && r < hi) slist[r - lo] = t * 16 + k;
                ++r;
            }
        }
    }
    __syncthreads();                               // barrier #2 (drains glds)

    // ---- 5. row i -> 32 float4 regs; pipelined sample loop ----
    float4 sr[32];
    #pragma unroll
    for (int u = 0; u < 32; ++u)
        sr[u] = smat[i * 32 + (u ^ (i & 31))];

    const float posv = pos[p * NDIM + i];

    int s = hf;
    if (s < nq) {
        const float4* y = reinterpret_cast<const float4*>(
            gaussian + (size_t)__builtin_amdgcn_readfirstlane(slist[s]) * NDIM);
        float4 A0=y[0],A1=y[1],A2=y[2],A3=y[3],A4=y[4],A5=y[5],A6=y[6],A7=y[7];
        float4 B0,B1,B2,B3,B4,B5,B6,B7;
        for (; s < nq; s += 2) {
            const int sid = __builtin_amdgcn_readfirstlane(slist[s]);
            y = reinterpret_cast<const float4*>(gaussian + (size_t)sid * NDIM);
            const int sn = (s + 2 < nq) ? __builtin_amdgcn_readfirstlane(slist[s + 2]) : sid;
            const float4* yn = reinterpret_cast<const float4*>(
                gaussian + (size_t)sn * NDIM);
            float a0 = 0.f, a1 = 0.f, a2 = 0.f, a3 = 0.f;
            B0=y[8];B1=y[9];B2=y[10];B3=y[11];B4=y[12];B5=y[13];B6=y[14];B7=y[15];
            DOT8(a0,a1,a2,a3, 0, A0,A1,A2,A3,A4,A5,A6,A7)
            A0=y[16];A1=y[17];A2=y[18];A3=y[19];A4=y[20];A5=y[21];A6=y[22];A7=y[23];
            DOT8(a0,a1,a2,a3, 8, B0,B1,B2,B3,B4,B5,B6,B7)
            B0=y[24];B1=y[25];B2=y[26];B3=y[27];B4=y[28];B5=y[29];B6=y[30];B7=y[31];
            DOT8(a0,a1,a2,a3, 16, A0,A1,A2,A3,A4,A5,A6,A7)
            A0=yn[0];A1=yn[1];A2=yn[2];A3=yn[3];A4=yn[4];A5=yn[5];A6=yn[6];A7=yn[7];
            DOT8(a0,a1,a2,a3, 24, B0,B1,B2,B3,B4,B5,B6,B7)
            out[sid * NDIM + i] = posv + ((a0 + a1) + (a2 + a3));
            if (i == 0) {
                wout[sid]   = pw;
                indout[sid] = (float)p;            // exact for 0..127
            }
        }
    }
}

extern "C" void kernel_launch(void* const* d_in, const int* in_sizes, int n_in,
                              void* d_out, int out_size, void* d_ws, size_t ws_size,
                              hipStream_t stream) {
    const float* gaussian = (const float*)d_in[0];   // [4096,128]
    const float* logp     = (const float*)d_in[1];   // [128,1]
    const float* pos      = (const float*)d_in[2];   // [128,128]
    const float* sigma    = (const float*)d_in[3];   // [128,128,128]
    const int*   randind  = (const int*)d_in[4];     // [4096]

    float* out    = (float*)d_out;            // [4096*128]
    float* wout   = out + BATCH * NDIM;       // [4096]
    float* indout = wout + BATCH;             // [4096]

    mix_kernel<<<NBLK, 256, 0, stream>>>(gaussian, logp, pos, sigma, randind,
                                         out, wout, indout);
}